// Round 3
// 436.850 us; speedup vs baseline: 1.1185x; 1.1185x over previous
//
#include <hip/hip_runtime.h>
#include <stdint.h>

#define M_DIM 8192
#define K_DIM 4096
#define O_DIM 4096
#define NWORDS 128

typedef __attribute__((ext_vector_type(8))) short bf16x8;
typedef __attribute__((ext_vector_type(4))) float f32x4;
typedef __attribute__((ext_vector_type(4))) float fvec4;
typedef __attribute__((ext_vector_type(4))) unsigned uvec4;
typedef __attribute__((ext_vector_type(2))) unsigned uvec2;

__device__ __forceinline__ unsigned f32_to_bf16u(float f) {
  union { float f; unsigned u; } v; v.f = f;
  return (v.u + 0x7FFFu + ((v.u >> 16) & 1u)) >> 16;   // round-to-nearest-even
}

__device__ __forceinline__ unsigned pack_bf16x2(float lo, float hi) {
  return f32_to_bf16u(lo) | (f32_to_bf16u(hi) << 16);
}

// ---- phase 1 (merged): x fp32->bf16 AND ternary unpack, one launch ----------
__global__ __launch_bounds__(256) void prep_kernel(const fvec4* __restrict__ x,
                                                   uvec2* __restrict__ xb,
                                                   const unsigned* __restrict__ nz,
                                                   const unsigned* __restrict__ sgn,
                                                   unsigned short* __restrict__ wb) {
  const int b   = blockIdx.x;
  const int tid = threadIdx.x;
  if (b < 8192) {
    const long base = (long)b * 1024 + tid;
#pragma unroll
    for (int j = 0; j < 4; ++j) {
      const long g = base + j * 256;
      const fvec4 v = x[g];
      uvec2 o;
      o.x = pack_bf16x2(v.x, v.y);
      o.y = pack_bf16x2(v.z, v.w);
      xb[g] = o;
    }
  } else {
    const int i = (b - 8192) * 256 + tid;   // (word, q) pair id
    const int w = i >> 2;
    const int q = i & 3;
    const unsigned n = nz[w] >> (8 * q);
    const unsigned s = sgn[w] >> (8 * q);
    unsigned out[4];
#pragma unroll
    for (int p = 0; p < 4; ++p) {
      const int j0 = 2 * p, j1 = 2 * p + 1;
      unsigned lo = ((n >> j0) & 1u) ? (0x3F80u | (((s >> j0) & 1u) << 15)) : 0u;
      unsigned hi = ((n >> j1) & 1u) ? (0x3F80u | (((s >> j1) & 1u) << 15)) : 0u;
      out[p] = lo | (hi << 16);
    }
    uvec4 v = { out[0], out[1], out[2], out[3] };
    *(uvec4*)(wb + (long)w * 32 + q * 8) = v;
  }
}

// ---- phase 2: bf16 GEMM, 256x256 tile, BK=64, 8-wave, 8-phase pipeline ------
// RACE-FIXED schedule (R1 post-mortem). Per-phase read/write sets are disjoint
// and every stage into a region is issued only after the barrier following its
// last ds_read. Reads: p1 = A-TQ0 + ALL 4 B frags (bv[4][2] held in regs so B
// halves are read in exactly one phase); p3 = A-TQ1; p5/p7 mirror (buf1).
// Stages (1 half-tile/phase, stream order per tile = [B0,B1,A0,A1]):
//   p1: A1(T+1)  p2: B0(T+2)  p3: B1(T+2)  p4: A0(T+2)+vmcnt(6)
//   p5: A1(T+2)  p6: B0(T+3)  p7: B1(T+3)  p8: A0(T+3)+vmcnt(6)
// vmcnt(6) at p4 drains all of T+1 (read at p5); at p8 drains all of T+2
// (read at next p1). Steady state: 3 half-tiles (6 loads) in flight.
__global__ __launch_bounds__(512, 2) void gemm_kernel(const unsigned short* __restrict__ A,
                                                      const unsigned short* __restrict__ B,
                                                      const float* __restrict__ bias,
                                                      const float* __restrict__ alpha,
                                                      float* __restrict__ C) {
  __shared__ unsigned short lds[65536];   // 128 KiB: A [buf][half] then B

  const int tid  = threadIdx.x;
  const int lane = tid & 63;
  const int wave = tid >> 6;        // 8 waves: 2(M) x 4(N)
  const int wm   = wave >> 2;       // M offset wm*128
  const int wn   = wave & 3;        // N offset wn*64

  // XCD-aware bijective swizzle (nwg = 512, divisible by 8)
  const int wg   = blockIdx.x;
  const int swz  = (wg & 7) * 64 + (wg >> 3);
  const int nBlk = (swz & 15) * 256;
  const int mBlk = (swz >> 4) * 256;

  const unsigned short* Apan = A + (long)mBlk * K_DIM;
  const unsigned short* Bpan = B + (long)nBlk * K_DIM;

  // staging map: half-tile = 128x64 bf16 = 16 KiB = 1024 chunks of 16 B.
  // LDS dest linear (wave-uniform base + lane*16, m104); SOURCE carries the
  // inverse swizzle (rule 21).
  int lOff[2], gOff[2];
#pragma unroll
  for (int l = 0; l < 2; ++l) {
    const int o = (l * 512 + tid) * 16;           // LDS byte offset in half slot
    const int r = o >> 7;                         // row (128 B per row)
    const int q = ((o >> 4) & 7) ^ (r & 7);       // global chunk (inverse swz)
    lOff[l] = o;
    gOff[l] = r * K_DIM + q * 8;                  // shorts
  }

  // fragment addressing (identical lane mapping to the verified 128^2 kernel)
  const int fr  = lane & 15;                      // row within 16-frag
  const int fq  = lane >> 4;                      // k-quad
  const int sl0 = fq ^ (fr & 7);                  // chunk slot kh=0 (kh=1: ^4)
  const int aFB = fr * 64;                        // shorts
  const int bFB = (wn & 1) * 4096 + fr * 64;
  const int A0S = wm * 8192;                      // A buf0, half wm
  const int A1S = (2 + wm) * 8192;                // A buf1, half wm
  const int B0S = 32768 + (wn >> 1) * 8192;       // B buf0, half wn>>1
  const int B1S = 32768 + (2 + (wn >> 1)) * 8192; // B buf1, half wn>>1

  f32x4  acc[8][4] = {};
  bf16x8 a[4][2], bv[4][2];

#define STAGE(SUBv, BUFv, TILEv) do {                                          \
    const unsigned short* s_ = (((SUBv) < 2) ? Apan : Bpan)                    \
        + (long)((SUBv) & 1) * (128 * K_DIM) + (long)(TILEv) * 64;             \
    const int dB = ((((SUBv) < 2) ? 0 : 32768)                                 \
        + (((BUFv) * 2) + ((SUBv) & 1)) * 8192) * 2;                           \
    __builtin_amdgcn_global_load_lds(                                          \
        (const __attribute__((address_space(1))) void*)(s_ + gOff[0]),         \
        (__attribute__((address_space(3))) void*)((char*)lds + dB + lOff[0]),  \
        16, 0, 0);                                                             \
    __builtin_amdgcn_global_load_lds(                                          \
        (const __attribute__((address_space(1))) void*)(s_ + gOff[1]),         \
        (__attribute__((address_space(3))) void*)((char*)lds + dB + lOff[1]),  \
        16, 0, 0);                                                             \
  } while (0)

#define LOADA(BASE, TQ)                                                        \
  _Pragma("unroll")                                                            \
  for (int i = 0; i < 4; ++i) {                                                \
    const int off_ = (BASE) + ((TQ) * 4 + i) * 1024 + aFB;                     \
    a[i][0] = *(const bf16x8*)(lds + off_ + sl0 * 8);                          \
    a[i][1] = *(const bf16x8*)(lds + off_ + (sl0 ^ 4) * 8);                    \
  }

#define LOADB(BASE)                                                            \
  _Pragma("unroll")                                                            \
  for (int j = 0; j < 4; ++j) {                                                \
    const int off_ = (BASE) + bFB + j * 1024;                                  \
    bv[j][0] = *(const bf16x8*)(lds + off_ + sl0 * 8);                         \
    bv[j][1] = *(const bf16x8*)(lds + off_ + (sl0 ^ 4) * 8);                   \
  }

#define MFMAQ(QM, QN)                                                          \
  _Pragma("unroll")                                                            \
  for (int kh = 0; kh < 2; ++kh)                                               \
    _Pragma("unroll")                                                          \
    for (int i = 0; i < 4; ++i)                                                \
      _Pragma("unroll")                                                        \
      for (int j = 0; j < 2; ++j)                                              \
        acc[(QM) * 4 + i][(QN) * 2 + j] = __builtin_amdgcn_mfma_f32_16x16x32_bf16( \
            a[i][kh], bv[(QN) * 2 + j][kh], acc[(QM) * 4 + i][(QN) * 2 + j], 0, 0, 0);

#define MID()  __builtin_amdgcn_s_barrier();                                   \
               asm volatile("s_waitcnt lgkmcnt(0)" ::: "memory");              \
               __builtin_amdgcn_s_setprio(1)
#define ENDPH()   __builtin_amdgcn_s_setprio(0); __builtin_amdgcn_s_barrier()
#define ENDVM6()  __builtin_amdgcn_s_setprio(0);                               \
                  asm volatile("s_waitcnt vmcnt(6)" ::: "memory");             \
                  __builtin_amdgcn_s_barrier()
#define ENDVM0()  __builtin_amdgcn_s_setprio(0);                               \
                  asm volatile("s_waitcnt vmcnt(0)" ::: "memory");             \
                  __builtin_amdgcn_s_barrier()

  // ---- prologue: tile0 all 4 halves + tile1 {B0,B1,A0} ----
  STAGE(2, 0, 0); STAGE(3, 0, 0); STAGE(0, 0, 0); STAGE(1, 0, 0);
  STAGE(2, 1, 1); STAGE(3, 1, 1); STAGE(0, 1, 1);
  asm volatile("s_waitcnt vmcnt(6)" ::: "memory");   // tile 0 fully landed
  __builtin_amdgcn_s_barrier();

  // ---- main loop: 31 iterations, computing tiles 0..61 ----
  for (int it = 0; it < (K_DIM / 64) / 2 - 1; ++it) {
    const int t1 = 2 * it + 1, t2 = 2 * it + 2, t3 = 2 * it + 3;
    // p1..p4: tile 2it (buf0)
    LOADA(A0S, 0); LOADB(B0S); STAGE(1, 1, t1); MID(); MFMAQ(0, 0); ENDPH();
                               STAGE(2, 0, t2); MID(); MFMAQ(0, 1); ENDPH();
    LOADA(A0S, 1);             STAGE(3, 0, t2); MID(); MFMAQ(1, 0); ENDPH();
                               STAGE(0, 0, t2); MID(); MFMAQ(1, 1); ENDVM6();
    // p5..p8: tile 2it+1 (buf1)
    LOADA(A1S, 0); LOADB(B1S); STAGE(1, 0, t2); MID(); MFMAQ(0, 0); ENDPH();
                               STAGE(2, 1, t3); MID(); MFMAQ(0, 1); ENDPH();
    LOADA(A1S, 1);             STAGE(3, 1, t3); MID(); MFMAQ(1, 0); ENDPH();
                               STAGE(0, 1, t3); MID(); MFMAQ(1, 1); ENDVM6();
  }

  // ---- epilogue: tile 62 (buf0) + tile 63 (buf1); only A1(63) left to stage
  LOADA(A0S, 0); LOADB(B0S); STAGE(1, 1, 63); MID(); MFMAQ(0, 0); ENDPH();
                                              MID(); MFMAQ(0, 1); ENDPH();
  LOADA(A0S, 1);                              MID(); MFMAQ(1, 0); ENDPH();
                                              MID(); MFMAQ(1, 1); ENDVM0();
  LOADA(A1S, 0); LOADB(B1S);                  MID(); MFMAQ(0, 0); ENDPH();
                                              MID(); MFMAQ(0, 1); ENDPH();
  LOADA(A1S, 1);                              MID(); MFMAQ(1, 0); ENDPH();
                                              MID(); MFMAQ(1, 1);
  __builtin_amdgcn_s_setprio(0);

  // ---- C write: C[m][n] = acc * alpha[n] + bias[n] (nontemporal, write-once)
  // C/D layout (verified m89/m91): col = lane&15, row = (lane>>4)*4 + reg
#pragma unroll
  for (int tn = 0; tn < 4; ++tn) {
    const int n = nBlk + wn * 64 + tn * 16 + fr;
    const float al = alpha[n];
    const float bi = bias[n];
#pragma unroll
    for (int tm = 0; tm < 8; ++tm) {
      const int mBase = mBlk + wm * 128 + tm * 16 + fq * 4;
#pragma unroll
      for (int r = 0; r < 4; ++r)
        __builtin_nontemporal_store(acc[tm][tn][r] * al + bi,
                                    C + (long)(mBase + r) * O_DIM + n);
    }
  }

#undef STAGE
#undef LOADA
#undef LOADB
#undef MFMAQ
#undef MID
#undef ENDPH
#undef ENDVM6
#undef ENDVM0
}

// ---- fallback (ws too small): slow but correct fp32 path --------------------
__global__ __launch_bounds__(256) void fallback_kernel(const float* __restrict__ x,
                                                       const unsigned* __restrict__ nz,
                                                       const unsigned* __restrict__ sgn,
                                                       const float* __restrict__ bias,
                                                       const float* __restrict__ alpha,
                                                       float* __restrict__ y) {
  long gid = (long)blockIdx.x * 256 + threadIdx.x;
  int o = (int)(gid % O_DIM);
  long m = gid / O_DIM;
  const float* xr = x + m * K_DIM;
  float s = 0.f;
  for (int w = 0; w < NWORDS; ++w) {
    unsigned n = nz[o * NWORDS + w];
    unsigned g = sgn[o * NWORDS + w];
    for (int j = 0; j < 32; ++j) {
      if ((n >> j) & 1u) {
        float v = xr[w * 32 + j];
        s += ((g >> j) & 1u) ? -v : v;
      }
    }
  }
  y[gid] = s * alpha[o] + bias[o];
}

extern "C" void kernel_launch(void* const* d_in, const int* in_sizes, int n_in,
                              void* d_out, int out_size, void* d_ws, size_t ws_size,
                              hipStream_t stream) {
  const float*    x     = (const float*)d_in[0];
  const unsigned* nz    = (const unsigned*)d_in[1];
  const unsigned* sgn   = (const unsigned*)d_in[2];
  const float*    bias  = (const float*)d_in[3];
  const float*    alpha = (const float*)d_in[4];
  float*          y     = (float*)d_out;

  const size_t xb_bytes = (size_t)M_DIM * K_DIM * 2;   // 64 MiB
  const size_t wb_bytes = (size_t)O_DIM * K_DIM * 2;   // 32 MiB

  if (ws_size >= xb_bytes + wb_bytes) {
    unsigned short* xb = (unsigned short*)d_ws;
    unsigned short* wb = (unsigned short*)((char*)d_ws + xb_bytes);

    prep_kernel<<<16384, 256, 0, stream>>>((const fvec4*)x, (uvec2*)xb, nz, sgn, wb);
    gemm_kernel<<<512, 512, 0, stream>>>(xb, wb, bias, alpha, y);
  } else {
    fallback_kernel<<<(long)M_DIM * O_DIM / 256, 256, 0, stream>>>(x, nz, sgn, bias, alpha, y);
  }
}

// Round 4
// 435.257 us; speedup vs baseline: 1.1226x; 1.0037x over previous
//
#include <hip/hip_runtime.h>
#include <stdint.h>

#define M_DIM 8192
#define K_DIM 4096
#define O_DIM 4096
#define NWORDS 128

typedef __attribute__((ext_vector_type(8))) short bf16x8;
typedef __attribute__((ext_vector_type(4))) float f32x4;
typedef __attribute__((ext_vector_type(4))) float fvec4;
typedef __attribute__((ext_vector_type(4))) unsigned uvec4;

__device__ __forceinline__ unsigned f32_to_bf16u(float f) {
  union { float f; unsigned u; } v; v.f = f;
  return (v.u + 0x7FFFu + ((v.u >> 16) & 1u)) >> 16;   // round-to-nearest-even
}

__device__ __forceinline__ unsigned pack_bf16x2(float lo, float hi) {
  return f32_to_bf16u(lo) | (f32_to_bf16u(hi) << 16);
}

// ---- phase 1: x fp32->bf16 AND ternary unpack, grid-stride, 16 B stores -----
// Blocks [0,2048): cvt. 524288 threads x 8 iters; per iter load 2 adjacent
// fvec4 (32 B) -> store 1 uvec4 (16 B). Wave covers 2 KiB contiguous per iter.
// Blocks [2048,2560): unpack. 131072 threads x 16 iters; 16 B uvec4 stores.
__global__ __launch_bounds__(256) void prep_kernel(const fvec4* __restrict__ x,
                                                   uvec4* __restrict__ xb4,
                                                   const unsigned* __restrict__ nz,
                                                   const unsigned* __restrict__ sgn,
                                                   unsigned short* __restrict__ wb) {
  const int b   = blockIdx.x;
  const int tid = threadIdx.x;
  if (b < 2048) {
    // pairs of fvec4: M*K/8 = 4194304 total; stride 2048*256 = 524288
    for (long p = (long)b * 256 + tid; p < 4194304; p += 524288) {
      const fvec4 v0 = x[2 * p];
      const fvec4 v1 = x[2 * p + 1];
      uvec4 o;
      o.x = pack_bf16x2(v0.x, v0.y);
      o.y = pack_bf16x2(v0.z, v0.w);
      o.z = pack_bf16x2(v1.x, v1.y);
      o.w = pack_bf16x2(v1.z, v1.w);
      xb4[p] = o;
    }
  } else {
    // chunks: O*K/8 = 2097152 total; stride 512*256 = 131072
    for (long i = (long)(b - 2048) * 256 + tid; i < 2097152; i += 131072) {
      const int w = (int)(i >> 2);
      const int q = (int)(i & 3);
      const unsigned n = nz[w] >> (8 * q);
      const unsigned s = sgn[w] >> (8 * q);
      unsigned out[4];
#pragma unroll
      for (int pq = 0; pq < 4; ++pq) {
        const int j0 = 2 * pq, j1 = 2 * pq + 1;
        unsigned lo = ((n >> j0) & 1u) ? (0x3F80u | (((s >> j0) & 1u) << 15)) : 0u;
        unsigned hi = ((n >> j1) & 1u) ? (0x3F80u | (((s >> j1) & 1u) << 15)) : 0u;
        out[pq] = lo | (hi << 16);
      }
      uvec4 v = { out[0], out[1], out[2], out[3] };
      *(uvec4*)(wb + (long)w * 32 + q * 8) = v;
    }
  }
}

// ---- phase 2: bf16 GEMM, 256x256 tile, BK=64, 8-wave, 8-phase pipeline v2 ---
// v2 (R3 post-mortem): even ds_read distribution. MFMA grouped 2-M-rows x 4-N
// per phase -> reads 12/4/4/4 per half-iter (a[2][2] live, bv[4][2] cached;
// every LDS word read exactly once). lgkmcnt(8) partial pre-drain on 12-read
// phases (template's optional drain).
// Read completion: B-buf fully read at p1/p5; A-buf fully read at p4/p8.
// Stages (1 half-tile/phase): p1:A1(T+1) p2:A0(T+1) p3:B0(T+2) p4:B1(T+2)
//   p5:A0(T+2) p6:A1(T+2) p7:B0(T+3) p8:B1(T+3)   (all windows verified)
// vmcnt(4) at p4: drains B(T+1),A1(T+1),A0(T+1) -> p5 reads safe.
// vmcnt(4) at p8: drains B(T+2),A0(T+2),A1(T+2) -> next p1 reads safe.
__global__ __launch_bounds__(512, 2) void gemm_kernel(const unsigned short* __restrict__ A,
                                                      const unsigned short* __restrict__ B,
                                                      const float* __restrict__ bias,
                                                      const float* __restrict__ alpha,
                                                      float* __restrict__ C) {
  __shared__ unsigned short lds[65536];   // 128 KiB: A [buf][half] then B

  const int tid  = threadIdx.x;
  const int lane = tid & 63;
  const int wave = tid >> 6;        // 8 waves: 2(M) x 4(N)
  const int wm   = wave >> 2;       // M offset wm*128
  const int wn   = wave & 3;        // N offset wn*64

  // XCD-aware bijective swizzle (nwg = 512, divisible by 8)
  const int wg   = blockIdx.x;
  const int swz  = (wg & 7) * 64 + (wg >> 3);
  const int nBlk = (swz & 15) * 256;
  const int mBlk = (swz >> 4) * 256;

  const unsigned short* Apan = A + (long)mBlk * K_DIM;
  const unsigned short* Bpan = B + (long)nBlk * K_DIM;

  // staging map: half-tile = 128x64 bf16 = 16 KiB = 1024 chunks of 16 B.
  // LDS dest linear (m104); SOURCE carries the inverse swizzle (rule 21).
  int lOff[2], gOff[2];
#pragma unroll
  for (int l = 0; l < 2; ++l) {
    const int o = (l * 512 + tid) * 16;           // LDS byte offset in half slot
    const int r = o >> 7;                         // row (128 B per row)
    const int q = ((o >> 4) & 7) ^ (r & 7);       // global chunk (inverse swz)
    lOff[l] = o;
    gOff[l] = r * K_DIM + q * 8;                  // shorts
  }

  // fragment addressing (verified lane mapping)
  const int fr  = lane & 15;                      // row within 16-frag
  const int fq  = lane >> 4;                      // k-quad
  const int sl0 = fq ^ (fr & 7);                  // chunk slot kh=0 (kh=1: ^4)
  const int aFB = fr * 64;                        // shorts
  const int bFB = (wn & 1) * 4096 + fr * 64;
  const int A0S = wm * 8192;                      // A buf0, half wm
  const int A1S = (2 + wm) * 8192;                // A buf1, half wm
  const int B0S = 32768 + (wn >> 1) * 8192;       // B buf0, half wn>>1
  const int B1S = 32768 + (2 + (wn >> 1)) * 8192; // B buf1, half wn>>1

  f32x4  acc[8][4] = {};
  bf16x8 a[2][2], bv[4][2];

#define STAGE(SUBv, BUFv, TILEv) do {                                          \
    const unsigned short* s_ = (((SUBv) < 2) ? Apan : Bpan)                    \
        + (long)((SUBv) & 1) * (128 * K_DIM) + (long)(TILEv) * 64;             \
    const int dB = ((((SUBv) < 2) ? 0 : 32768)                                 \
        + (((BUFv) * 2) + ((SUBv) & 1)) * 8192) * 2;                           \
    __builtin_amdgcn_global_load_lds(                                          \
        (const __attribute__((address_space(1))) void*)(s_ + gOff[0]),         \
        (__attribute__((address_space(3))) void*)((char*)lds + dB + lOff[0]),  \
        16, 0, 0);                                                             \
    __builtin_amdgcn_global_load_lds(                                          \
        (const __attribute__((address_space(1))) void*)(s_ + gOff[1]),         \
        (__attribute__((address_space(3))) void*)((char*)lds + dB + lOff[1]),  \
        16, 0, 0);                                                             \
  } while (0)

// a-frags for M-row-pair P (rows 32P..32P+31 of wave's A-half): 4 ds_read_b128
#define LOADA2(BASE, P)                                                        \
  _Pragma("unroll")                                                            \
  for (int i = 0; i < 2; ++i) {                                                \
    const int off_ = (BASE) + ((P) * 2 + i) * 1024 + aFB;                      \
    a[i][0] = *(const bf16x8*)(lds + off_ + sl0 * 8);                          \
    a[i][1] = *(const bf16x8*)(lds + off_ + (sl0 ^ 4) * 8);                    \
  }

// all 4 B frags of wave's half: 8 ds_read_b128 (only at p1/p5)
#define LOADB(BASE)                                                            \
  _Pragma("unroll")                                                            \
  for (int j = 0; j < 4; ++j) {                                                \
    const int off_ = (BASE) + bFB + j * 1024;                                  \
    bv[j][0] = *(const bf16x8*)(lds + off_ + sl0 * 8);                         \
    bv[j][1] = *(const bf16x8*)(lds + off_ + (sl0 ^ 4) * 8);                   \
  }

// 16 MFMA: M-row-pair P x all 4 N x both kh
#define MFMA2(P)                                                               \
  _Pragma("unroll")                                                            \
  for (int kh = 0; kh < 2; ++kh)                                               \
    _Pragma("unroll")                                                          \
    for (int i = 0; i < 2; ++i)                                                \
      _Pragma("unroll")                                                        \
      for (int tn = 0; tn < 4; ++tn)                                           \
        acc[(P) * 2 + i][tn] = __builtin_amdgcn_mfma_f32_16x16x32_bf16(        \
            a[i][kh], bv[tn][kh], acc[(P) * 2 + i][tn], 0, 0, 0);

#define PRE12()   asm volatile("s_waitcnt lgkmcnt(8)" ::: "memory")
#define MID()  __builtin_amdgcn_s_barrier();                                   \
               asm volatile("s_waitcnt lgkmcnt(0)" ::: "memory");              \
               __builtin_amdgcn_s_setprio(1)
#define ENDPH()   __builtin_amdgcn_s_setprio(0); __builtin_amdgcn_s_barrier()
#define ENDVM4()  __builtin_amdgcn_s_setprio(0);                               \
                  asm volatile("s_waitcnt vmcnt(4)" ::: "memory");             \
                  __builtin_amdgcn_s_barrier()
#define ENDVM0()  __builtin_amdgcn_s_setprio(0);                               \
                  asm volatile("s_waitcnt vmcnt(0)" ::: "memory");             \
                  __builtin_amdgcn_s_barrier()

  // ---- prologue: tile0 {B0,B1,A0,A1} + tile1 {B0,B1} ----
  STAGE(2, 0, 0); STAGE(3, 0, 0); STAGE(0, 0, 0); STAGE(1, 0, 0);
  STAGE(2, 1, 1); STAGE(3, 1, 1);
  asm volatile("s_waitcnt vmcnt(4)" ::: "memory");   // tile 0 fully landed
  __builtin_amdgcn_s_barrier();

  // ---- main loop: 31 iterations, computing tiles 0..61 ----
  for (int it = 0; it < (K_DIM / 64) / 2 - 1; ++it) {
    const int t1 = 2 * it + 1, t2 = 2 * it + 2, t3 = 2 * it + 3;
    // p1..p4: tile 2it (buf0)
    LOADA2(A0S, 0); LOADB(B0S); STAGE(1, 1, t1); PRE12();
                                                 MID(); MFMA2(0); ENDPH();
    LOADA2(A0S, 1);             STAGE(0, 1, t1); MID(); MFMA2(1); ENDPH();
    LOADA2(A0S, 2);             STAGE(2, 0, t2); MID(); MFMA2(2); ENDPH();
    LOADA2(A0S, 3);             STAGE(3, 0, t2); MID(); MFMA2(3); ENDVM4();
    // p5..p8: tile 2it+1 (buf1)
    LOADA2(A1S, 0); LOADB(B1S); STAGE(0, 0, t2); PRE12();
                                                 MID(); MFMA2(0); ENDPH();
    LOADA2(A1S, 1);             STAGE(1, 0, t2); MID(); MFMA2(1); ENDPH();
    LOADA2(A1S, 2);             STAGE(2, 1, t3); MID(); MFMA2(2); ENDPH();
    LOADA2(A1S, 3);             STAGE(3, 1, t3); MID(); MFMA2(3); ENDVM4();
  }

  // ---- epilogue: tile 62 (buf0) + tile 63 (buf1); A1(63),A0(63) to stage ----
  LOADA2(A0S, 0); LOADB(B0S); STAGE(1, 1, 63); PRE12();
                                               MID(); MFMA2(0); ENDPH();
  LOADA2(A0S, 1);             STAGE(0, 1, 63); MID(); MFMA2(1); ENDPH();
  LOADA2(A0S, 2);                              MID(); MFMA2(2); ENDPH();
  LOADA2(A0S, 3);                              MID(); MFMA2(3); ENDVM0();
  LOADA2(A1S, 0); LOADB(B1S);                  MID(); MFMA2(0); ENDPH();
  LOADA2(A1S, 1);                              MID(); MFMA2(1); ENDPH();
  LOADA2(A1S, 2);                              MID(); MFMA2(2); ENDPH();
  LOADA2(A1S, 3);                              MID(); MFMA2(3);
  __builtin_amdgcn_s_setprio(0);

  // ---- C write: C[m][n] = acc * alpha[n] + bias[n] (nontemporal, write-once)
  // C/D layout (verified m89/m91): col = lane&15, row = (lane>>4)*4 + reg
#pragma unroll
  for (int tn = 0; tn < 4; ++tn) {
    const int n = nBlk + wn * 64 + tn * 16 + fr;
    const float al = alpha[n];
    const float bi = bias[n];
#pragma unroll
    for (int tm = 0; tm < 8; ++tm) {
      const int mBase = mBlk + wm * 128 + tm * 16 + fq * 4;
#pragma unroll
      for (int r = 0; r < 4; ++r)
        __builtin_nontemporal_store(acc[tm][tn][r] * al + bi,
                                    C + (long)(mBase + r) * O_DIM + n);
    }
  }

#undef STAGE
#undef LOADA2
#undef LOADB
#undef MFMA2
#undef PRE12
#undef MID
#undef ENDPH
#undef ENDVM4
#undef ENDVM0
}

// ---- fallback (ws too small): slow but correct fp32 path --------------------
__global__ __launch_bounds__(256) void fallback_kernel(const float* __restrict__ x,
                                                       const unsigned* __restrict__ nz,
                                                       const unsigned* __restrict__ sgn,
                                                       const float* __restrict__ bias,
                                                       const float* __restrict__ alpha,
                                                       float* __restrict__ y) {
  long gid = (long)blockIdx.x * 256 + threadIdx.x;
  int o = (int)(gid % O_DIM);
  long m = gid / O_DIM;
  const float* xr = x + m * K_DIM;
  float s = 0.f;
  for (int w = 0; w < NWORDS; ++w) {
    unsigned n = nz[o * NWORDS + w];
    unsigned g = sgn[o * NWORDS + w];
    for (int j = 0; j < 32; ++j) {
      if ((n >> j) & 1u) {
        float v = xr[w * 32 + j];
        s += ((g >> j) & 1u) ? -v : v;
      }
    }
  }
  y[gid] = s * alpha[o] + bias[o];
}

extern "C" void kernel_launch(void* const* d_in, const int* in_sizes, int n_in,
                              void* d_out, int out_size, void* d_ws, size_t ws_size,
                              hipStream_t stream) {
  const float*    x     = (const float*)d_in[0];
  const unsigned* nz    = (const unsigned*)d_in[1];
  const unsigned* sgn   = (const unsigned*)d_in[2];
  const float*    bias  = (const float*)d_in[3];
  const float*    alpha = (const float*)d_in[4];
  float*          y     = (float*)d_out;

  const size_t xb_bytes = (size_t)M_DIM * K_DIM * 2;   // 64 MiB
  const size_t wb_bytes = (size_t)O_DIM * K_DIM * 2;   // 32 MiB

  if (ws_size >= xb_bytes + wb_bytes) {
    unsigned short* xb = (unsigned short*)d_ws;
    unsigned short* wb = (unsigned short*)((char*)d_ws + xb_bytes);

    prep_kernel<<<2560, 256, 0, stream>>>((const fvec4*)x, (uvec4*)xb, nz, sgn, wb);
    gemm_kernel<<<512, 512, 0, stream>>>(xb, wb, bias, alpha, y);
  } else {
    fallback_kernel<<<(long)M_DIM * O_DIM / 256, 256, 0, stream>>>(x, nz, sgn, bias, alpha, y);
  }
}